// Round 3
// baseline (1115.226 us; speedup 1.0000x reference)
//
#include <hip/hip_runtime.h>
#include <hip/hip_bf16.h>
#include <stdint.h>

#define N_B 4
#define NV 4096
#define NE 2048
#define NC 64

// async global->LDS, 16B per lane. LDS dest must be wave-uniform-base + lane*16.
__device__ __forceinline__ void gload_lds16(const void* g, void* l) {
    __builtin_amdgcn_global_load_lds(
        (const __attribute__((address_space(1))) uint32_t*)g,
        (__attribute__((address_space(3))) uint32_t*)l, 16, 0, 0);
}

// ---------------------------------------------------------------------------
// Kernel 1: Y[n,v,c] = sum_k x[n,v,k] * theta[k,c]
// ---------------------------------------------------------------------------
__global__ __launch_bounds__(256) void k_xtheta(const float* __restrict__ x,
                                                const float* __restrict__ th,
                                                float* __restrict__ Y) {
    __shared__ float ths[64][64];
    __shared__ float xs[4][64];
    const int t = threadIdx.x;

    const float4* tsrc = reinterpret_cast<const float4*>(th);
    float4* tdst = reinterpret_cast<float4*>(&ths[0][0]);
#pragma unroll
    for (int i = 0; i < 4; ++i) tdst[t + i * 256] = tsrc[t + i * 256];

    const size_t row0 = (size_t)blockIdx.x * 4;
    xs[t >> 6][t & 63] = x[row0 * 64 + t];
    __syncthreads();

    const int r = t >> 6;
    const int c = t & 63;
    float acc = 0.f;
#pragma unroll
    for (int k = 0; k < 64; ++k) acc += xs[r][k] * ths[k][c];
    Y[row0 * 64 + t] = acc;
}

// ---------------------------------------------------------------------------
// Kernel 2: vertex -> edge partials (NO atomics).
//   P2[sp][n,e,c] = sum_{v in Krange} H[n,v,e] * Y[n,v,c]
//   deP[sp][n,e]  = sum_{v in Krange} H[n,v,e]
// Tile 128e x 64c, K_STEP=32, depth-1 async prefetch via global_load_lds.
// Thread: 4e x 8c outer product. grid = (NE/128, split2, N).
// ---------------------------------------------------------------------------
__global__ __launch_bounds__(256, 3) void k_v2e(const float* __restrict__ H,
                                                const float* __restrict__ Y,
                                                float* __restrict__ P2,
                                                float* __restrict__ deP) {
    __shared__ float Ht[2][32][128];   // 32 KB
    __shared__ float Yt[2][32][64];    // 16 KB

    const int n      = blockIdx.z;
    const int e0     = blockIdx.x * 128;
    const int nsp    = gridDim.y;
    const int krange = NV / nsp;            // multiple of 32 by construction
    const int kk0    = blockIdx.y * krange;
    const int S      = krange / 32;

    const int t  = threadIdx.x;
    const int w  = t >> 6;      // wave id
    const int l  = t & 63;      // lane
    const int gc = t & 7;       // c-group (8 groups x 8c)
    const int ge = t >> 3;      // e-group (32 groups x 4e)
    const int c8 = gc * 8;
    const int e4 = ge * 4;

    const float* Hn = H + (size_t)n * NV * NE;
    const float* Yn = Y + (size_t)n * NV * NC;

    float acc[4][8] = {};
    float dsum[4] = {0.f, 0.f, 0.f, 0.f};

    // stage tile for v-rows [v0, v0+32): H 32x128 (16KB), Y 32x64 (8KB)
    auto STAGE = [&](int buf, int v0) {
        float* hb = &Ht[buf][0][0];
        float* yb = &Yt[buf][0][0];
#pragma unroll
        for (int i = 0; i < 4; ++i) {
            const int r = w * 8 + i * 2 + (l >> 5);        // 0..31
            gload_lds16(Hn + (size_t)(v0 + r) * NE + e0 + (l & 31) * 4,
                        hb + (w * 1024 + i * 256 + l * 4));
        }
#pragma unroll
        for (int i = 0; i < 2; ++i) {
            const int fofs = w * 512 + i * 256 + l * 4;
            gload_lds16(Yn + (size_t)v0 * NC + fofs, yb + fofs);
        }
    };

    STAGE(0, kk0);
    asm volatile("s_waitcnt vmcnt(0)" ::: "memory");
    __syncthreads();

    int cur = 0;
    for (int s = 0; s < S; ++s) {
        if (s + 1 < S) STAGE(cur ^ 1, kk0 + (s + 1) * 32);   // prefetch next
#pragma unroll
        for (int k = 0; k < 32; ++k) {
            const float4 h  = *reinterpret_cast<const float4*>(&Ht[cur][k][e4]);
            const float4 y0 = *reinterpret_cast<const float4*>(&Yt[cur][k][c8]);
            const float4 y1 = *reinterpret_cast<const float4*>(&Yt[cur][k][c8 + 4]);
            const float hv[4] = {h.x, h.y, h.z, h.w};
            const float yv[8] = {y0.x, y0.y, y0.z, y0.w, y1.x, y1.y, y1.z, y1.w};
#pragma unroll
            for (int i = 0; i < 4; ++i) {
                dsum[i] += hv[i];
#pragma unroll
                for (int j = 0; j < 8; ++j) acc[i][j] += hv[i] * yv[j];
            }
        }
        asm volatile("s_waitcnt vmcnt(0)" ::: "memory");
        __syncthreads();
        cur ^= 1;
    }

    const int sp = blockIdx.y;
    float* pb = P2 + (((size_t)sp * N_B + n) * NE + (e0 + e4)) * NC + c8;
#pragma unroll
    for (int i = 0; i < 4; ++i) {
        *reinterpret_cast<float4*>(pb + (size_t)i * NC) =
            make_float4(acc[i][0], acc[i][1], acc[i][2], acc[i][3]);
        *reinterpret_cast<float4*>(pb + (size_t)i * NC + 4) =
            make_float4(acc[i][4], acc[i][5], acc[i][6], acc[i][7]);
    }
    if (gc == 0) {
        float* db = deP + ((size_t)sp * N_B + n) * NE + e0 + e4;
#pragma unroll
        for (int i = 0; i < 4; ++i) db[i] = dsum[i];
    }
}

// ---------------------------------------------------------------------------
// Kernel 3: reduce stage-2 partials, scale by 1/de:  Z = (sum_s P2) / de
// In-place safe when Z == P2 and nsp == 1.
// ---------------------------------------------------------------------------
__global__ __launch_bounds__(256) void k_red2(const float* __restrict__ P2,
                                              const float* __restrict__ deP,
                                              float* __restrict__ Z, int nsp) {
    const int i = blockIdx.x * 256 + threadIdx.x;     // float4 index
    const int row = i >> 4;                           // n*E + e
    float4 a = make_float4(0.f, 0.f, 0.f, 0.f);
    float d = 0.f;
    for (int s = 0; s < nsp; ++s) {
        const float4 p = reinterpret_cast<const float4*>(P2)[(size_t)s * (N_B * NE * NC / 4) + i];
        a.x += p.x; a.y += p.y; a.z += p.z; a.w += p.w;
        d += deP[(size_t)s * (N_B * NE) + row];
    }
    const float r = 1.0f / d;
    a.x *= r; a.y *= r; a.z *= r; a.w *= r;
    reinterpret_cast<float4*>(Z)[i] = a;
}

// ---------------------------------------------------------------------------
// Kernel 4: edge -> vertex partials (NO atomics).
//   P3[sp][n,v,c] = sum_{e in Krange} H[n,v,e] * Z[n,e,c]
//   dvP[sp][n,v]  = sum_{e in Krange} H[n,v,e]
// Tile 128v x 64c, K_STEP=32. H reg-staged + transposed LDS write (pad 132);
// Z via global_load_lds. Depth-1 prefetch.
// ---------------------------------------------------------------------------
__global__ __launch_bounds__(256, 3) void k_e2v(const float* __restrict__ H,
                                                const float* __restrict__ Z,
                                                float* __restrict__ P3,
                                                float* __restrict__ dvP) {
    __shared__ float Ht[2][32][132];   // [e_local][v_local], pad 132 (16B-aligned, conflict-free)
    __shared__ float Zt[2][32][64];

    const int n      = blockIdx.z;
    const int v0     = blockIdx.x * 128;
    const int nsp    = gridDim.y;
    const int krange = NE / nsp;
    const int kk0    = blockIdx.y * krange;
    const int S      = krange / 32;

    const int t  = threadIdx.x;
    const int w  = t >> 6;
    const int l  = t & 63;
    const int gc = t & 7;
    const int gv = t >> 3;
    const int c8 = gc * 8;
    const int v4 = gv * 4;

    const float* Hn = H + (size_t)n * NV * NE;
    const float* Zn = Z + (size_t)n * NE * NC;

    const int hrow = t >> 1;          // v_local 0..127
    const int eofs = (t & 1) * 16;    // e_local 0 or 16

    float acc[4][8] = {};
    float dsum[4] = {0.f, 0.f, 0.f, 0.f};
    float4 hreg[4];

    auto LOADH = [&](int ek) {
        const float* src = Hn + (size_t)(v0 + hrow) * NE + ek + eofs;
#pragma unroll
        for (int q = 0; q < 4; ++q) hreg[q] = *reinterpret_cast<const float4*>(src + q * 4);
    };
    auto GLZ = [&](int buf, int ek) {
        float* zb = &Zt[buf][0][0];
#pragma unroll
        for (int i = 0; i < 2; ++i) {
            const int fofs = w * 512 + i * 256 + l * 4;
            gload_lds16(Zn + (size_t)ek * NC + fofs, zb + fofs);
        }
    };
    auto WRH = [&](int buf) {
#pragma unroll
        for (int q = 0; q < 4; ++q) {
            Ht[buf][eofs + q * 4 + 0][hrow] = hreg[q].x;
            Ht[buf][eofs + q * 4 + 1][hrow] = hreg[q].y;
            Ht[buf][eofs + q * 4 + 2][hrow] = hreg[q].z;
            Ht[buf][eofs + q * 4 + 3][hrow] = hreg[q].w;
        }
    };

    // prologue: stage tile 0
    LOADH(kk0);
    GLZ(0, kk0);
    asm volatile("s_waitcnt vmcnt(0)" ::: "memory");
    WRH(0);
    __syncthreads();

    int cur = 0;
    for (int s = 0; s < S; ++s) {
        const int nxt = cur ^ 1;
        if (s + 1 < S) { LOADH(kk0 + (s + 1) * 32); GLZ(nxt, kk0 + (s + 1) * 32); }
#pragma unroll
        for (int k = 0; k < 32; ++k) {
            const float4 h  = *reinterpret_cast<const float4*>(&Ht[cur][k][v4]);
            const float4 y0 = *reinterpret_cast<const float4*>(&Zt[cur][k][c8]);
            const float4 y1 = *reinterpret_cast<const float4*>(&Zt[cur][k][c8 + 4]);
            const float hv[4] = {h.x, h.y, h.z, h.w};
            const float yv[8] = {y0.x, y0.y, y0.z, y0.w, y1.x, y1.y, y1.z, y1.w};
#pragma unroll
            for (int i = 0; i < 4; ++i) {
                dsum[i] += hv[i];
#pragma unroll
                for (int j = 0; j < 8; ++j) acc[i][j] += hv[i] * yv[j];
            }
        }
        asm volatile("s_waitcnt vmcnt(0)" ::: "memory");
        __syncthreads();                 // everyone done reading cur; Z(nxt) landed
        if (s + 1 < S) WRH(nxt);         // transpose-write H into nxt
        __syncthreads();                 // writes visible
        cur = nxt;
    }

    const int sp = blockIdx.y;
    float* pb = P3 + (((size_t)sp * N_B + n) * NV + v0 + v4) * NC + c8;
#pragma unroll
    for (int i = 0; i < 4; ++i) {
        *reinterpret_cast<float4*>(pb + (size_t)i * NC) =
            make_float4(acc[i][0], acc[i][1], acc[i][2], acc[i][3]);
        *reinterpret_cast<float4*>(pb + (size_t)i * NC + 4) =
            make_float4(acc[i][4], acc[i][5], acc[i][6], acc[i][7]);
    }
    if (gc == 0) {
        float* db = dvP + ((size_t)sp * N_B + n) * NV + v0 + v4;
#pragma unroll
        for (int i = 0; i < 4; ++i) db[i] = dsum[i];
    }
}

// ---------------------------------------------------------------------------
// Kernel 5: out = (sum_s P3) / dv + bias.  In-place safe when P3==out, nsp==1.
// ---------------------------------------------------------------------------
__global__ __launch_bounds__(256) void k_red3(const float* __restrict__ P3,
                                              const float* __restrict__ dvP,
                                              const float* __restrict__ bias,
                                              float* __restrict__ out, int nsp) {
    const int i = blockIdx.x * 256 + threadIdx.x;     // float4 index
    const int row = i >> 4;                           // n*V + v
    float4 a = make_float4(0.f, 0.f, 0.f, 0.f);
    float d = 0.f;
    for (int s = 0; s < nsp; ++s) {
        const float4 p = reinterpret_cast<const float4*>(P3)[(size_t)s * (N_B * NV * NC / 4) + i];
        a.x += p.x; a.y += p.y; a.z += p.z; a.w += p.w;
        d += dvP[(size_t)s * (N_B * NV) + row];
    }
    const float r = 1.0f / d;
    const float4 b = *reinterpret_cast<const float4*>(&bias[(i & 15) * 4]);
    a.x = a.x * r + b.x;
    a.y = a.y * r + b.y;
    a.z = a.z * r + b.z;
    a.w = a.w * r + b.w;
    reinterpret_cast<float4*>(out)[i] = a;
}

// ---------------------------------------------------------------------------
extern "C" void kernel_launch(void* const* d_in, const int* in_sizes, int n_in,
                              void* d_out, int out_size, void* d_ws, size_t ws_size,
                              hipStream_t stream) {
    const float* x     = (const float*)d_in[0];
    const float* H     = (const float*)d_in[1];
    const float* theta = (const float*)d_in[2];
    const float* bias  = (const float*)d_in[3];
    float* out = (float*)d_out;

    const size_t yN  = (size_t)N_B * NV * NC;   // 1,048,576
    const size_t zN  = (size_t)N_B * NE * NC;   //   524,288
    const size_t deN = (size_t)N_B * NE;        //     8,192
    const size_t dvN = (size_t)N_B * NV;        //    16,384

    auto need = [&](int a, int b) -> size_t {
        return (yN + (size_t)a * zN + (size_t)a * deN + zN + (size_t)b * yN + (size_t)b * dvN) * 4;
    };

    int s2, s3; bool minimal = false;
    if      (ws_size >= need(8, 4)) { s2 = 8; s3 = 4; }
    else if (ws_size >= need(4, 2)) { s2 = 4; s3 = 2; }
    else if (ws_size >= need(2, 1)) { s2 = 2; s3 = 1; }
    else                            { s2 = 1; s3 = 1; minimal = true; }

    float* Y   = (float*)d_ws;
    float* P2  = Y + yN;
    float* deP = P2 + (size_t)s2 * zN;
    float *Z, *P3, *dvP;
    if (minimal) {
        Z = P2;                 // red2 in place (s2==1)
        dvP = deP + deN;
        P3 = out;               // red3 in place (s3==1)
    } else {
        Z   = deP + (size_t)s2 * deN;
        P3  = Z + zN;
        dvP = P3 + (size_t)s3 * yN;
    }

    k_xtheta<<<dim3(N_B * NV / 4), 256, 0, stream>>>(x, theta, Y);
    k_v2e<<<dim3(NE / 128, s2, N_B), 256, 0, stream>>>(H, Y, P2, deP);
    k_red2<<<dim3((int)(zN / 4 / 256)), 256, 0, stream>>>(P2, deP, Z, s2);
    k_e2v<<<dim3(NV / 128, s3, N_B), 256, 0, stream>>>(H, Z, P3, dvP);
    k_red3<<<dim3((int)(yN / 4 / 256)), 256, 0, stream>>>(P3, dvP, bias, out, s3);
}

// Round 4
// 241.751 us; speedup vs baseline: 4.6131x; 4.6131x over previous
//
#include <hip/hip_runtime.h>
#include <hip/hip_bf16.h>
#include <stdint.h>

#define N_B 4
#define NV 4096
#define NE 2048
#define NC 64

// ---------------------------------------------------------------------------
// Kernel 1: Y[n,v,c] = sum_k x[n,v,k] * theta[k,c]
// ---------------------------------------------------------------------------
__global__ __launch_bounds__(256) void k_xtheta(const float* __restrict__ x,
                                                const float* __restrict__ th,
                                                float* __restrict__ Y) {
    __shared__ float ths[64][64];
    __shared__ float xs[4][64];
    const int t = threadIdx.x;

    const float4* tsrc = reinterpret_cast<const float4*>(th);
    float4* tdst = reinterpret_cast<float4*>(&ths[0][0]);
#pragma unroll
    for (int i = 0; i < 4; ++i) tdst[t + i * 256] = tsrc[t + i * 256];

    const size_t row0 = (size_t)blockIdx.x * 4;
    xs[t >> 6][t & 63] = x[row0 * 64 + t];
    __syncthreads();

    const int r = t >> 6;
    const int c = t & 63;
    float acc = 0.f;
#pragma unroll
    for (int k = 0; k < 64; ++k) acc += xs[r][k] * ths[k][c];
    Y[row0 * 64 + t] = acc;
}

// ---------------------------------------------------------------------------
// Kernel 2: vertex -> edge partials. NO LDS, NO barriers.
//   P2[sp][n,e,c] = sum_{v in Krange} H[n,v,e] * Y[n,v,c]
//   deP[sp][n,e]  = sum_{v in Krange} H[n,v,e]
// Tile 64e x 64c per block; thread = 4e x 4c outer product.
// h: coalesced 256B/wave/k from HBM (H read exactly once overall).
// y: 64B/wave/k broadcast loads from L2-resident Y.
// grid = (NE/64, split, N).
// ---------------------------------------------------------------------------
__global__ __launch_bounds__(256) void k_v2e(const float* __restrict__ H,
                                             const float* __restrict__ Y,
                                             float* __restrict__ P2,
                                             float* __restrict__ deP) {
    const int n      = blockIdx.z;
    const int e0     = blockIdx.x * 64;
    const int nsp    = gridDim.y;
    const int krange = NV / nsp;
    const int kk0    = blockIdx.y * krange;
    const int t      = threadIdx.x;
    const int e4     = (t & 15) * 4;
    const int c4     = (t >> 4) * 4;

    const float* __restrict__ hp = H + (size_t)n * NV * NE + (size_t)kk0 * NE + e0 + e4;
    const float* __restrict__ yp = Y + (size_t)n * NV * NC + (size_t)kk0 * NC + c4;

    float acc[4][4] = {};
    float ds[4] = {0.f, 0.f, 0.f, 0.f};

#pragma unroll 4
    for (int k = 0; k < krange; ++k) {
        const float4 h = *reinterpret_cast<const float4*>(hp);
        const float4 y = *reinterpret_cast<const float4*>(yp);
        hp += NE; yp += NC;
        ds[0] += h.x; ds[1] += h.y; ds[2] += h.z; ds[3] += h.w;
        acc[0][0] += h.x * y.x; acc[0][1] += h.x * y.y; acc[0][2] += h.x * y.z; acc[0][3] += h.x * y.w;
        acc[1][0] += h.y * y.x; acc[1][1] += h.y * y.y; acc[1][2] += h.y * y.z; acc[1][3] += h.y * y.w;
        acc[2][0] += h.z * y.x; acc[2][1] += h.z * y.y; acc[2][2] += h.z * y.z; acc[2][3] += h.z * y.w;
        acc[3][0] += h.w * y.x; acc[3][1] += h.w * y.y; acc[3][2] += h.w * y.z; acc[3][3] += h.w * y.w;
    }

    const int sp = blockIdx.y;
    float* pb = P2 + (((size_t)sp * N_B + n) * NE + e0 + e4) * NC + c4;
#pragma unroll
    for (int i = 0; i < 4; ++i)
        *reinterpret_cast<float4*>(pb + (size_t)i * NC) =
            make_float4(acc[i][0], acc[i][1], acc[i][2], acc[i][3]);

    if (c4 == 0) {
        float* db = deP + ((size_t)sp * N_B + n) * NE + e0 + e4;
#pragma unroll
        for (int i = 0; i < 4; ++i) db[i] = ds[i];
    }
}

// ---------------------------------------------------------------------------
// Kernel 3: reduce stage-2 partials, scale by 1/de:  Z = (sum_s P2) / de
// In-place safe when Z == P2 and nsp == 1.
// ---------------------------------------------------------------------------
__global__ __launch_bounds__(256) void k_red2(const float* __restrict__ P2,
                                              const float* __restrict__ deP,
                                              float* __restrict__ Z, int nsp) {
    const int i = blockIdx.x * 256 + threadIdx.x;     // float4 index
    const int row = i >> 4;                           // n*E + e
    float4 a = make_float4(0.f, 0.f, 0.f, 0.f);
    float d = 0.f;
    for (int s = 0; s < nsp; ++s) {
        const float4 p = reinterpret_cast<const float4*>(P2)[(size_t)s * (N_B * NE * NC / 4) + i];
        a.x += p.x; a.y += p.y; a.z += p.z; a.w += p.w;
        d += deP[(size_t)s * (N_B * NE) + row];
    }
    const float r = 1.0f / d;
    a.x *= r; a.y *= r; a.z *= r; a.w *= r;
    reinterpret_cast<float4*>(Z)[i] = a;
}

// ---------------------------------------------------------------------------
// Kernel 4: edge -> vertex partials.
//   P3[sp][n,v,c] = sum_{e in Krange} H[n,v,e] * Z[n,e,c]
//   dvP[sp][n,v]  = sum_{e in Krange} H[n,v,e]
// Tile 64v x 64c; H transposed through LDS [64][65] (2-way = free);
// z streamed from L2-resident Z (64B/wave/k). 1 ds_read_b128 per 16 FMA.
// grid = (NV/64, split, N).
// ---------------------------------------------------------------------------
__global__ __launch_bounds__(256) void k_e2v(const float* __restrict__ H,
                                             const float* __restrict__ Z,
                                             float* __restrict__ P3,
                                             float* __restrict__ dvP) {
    __shared__ float Ht[64][65];   // [e_local][v_local]

    const int n      = blockIdx.z;
    const int v0     = blockIdx.x * 64;
    const int nsp    = gridDim.y;
    const int krange = NE / nsp;
    const int kk0    = blockIdx.y * krange;
    const int S      = krange / 64;
    const int t      = threadIdx.x;
    const int v4     = (t & 15) * 4;
    const int c4     = (t >> 4) * 4;

    const float* __restrict__ Hn = H + (size_t)n * NV * NE;
    const float* __restrict__ Zn = Z + (size_t)n * NE * NC;

    const int srow = t >> 2;          // 0..63 : v row this thread stages
    const int scol = (t & 3) * 16;    // 0/16/32/48 : e-column strip

    float acc[4][4] = {};
    float ds[4] = {0.f, 0.f, 0.f, 0.f};

    for (int s = 0; s < S; ++s) {
        const int ek = kk0 + s * 64;
        // issue global loads for this tile before the barrier
        const float* src = Hn + (size_t)(v0 + srow) * NE + ek + scol;
        const float4 a = reinterpret_cast<const float4*>(src)[0];
        const float4 b = reinterpret_cast<const float4*>(src)[1];
        const float4 c = reinterpret_cast<const float4*>(src)[2];
        const float4 d = reinterpret_cast<const float4*>(src)[3];
        __syncthreads();   // previous step's reads complete
        Ht[scol +  0][srow] = a.x; Ht[scol +  1][srow] = a.y;
        Ht[scol +  2][srow] = a.z; Ht[scol +  3][srow] = a.w;
        Ht[scol +  4][srow] = b.x; Ht[scol +  5][srow] = b.y;
        Ht[scol +  6][srow] = b.z; Ht[scol +  7][srow] = b.w;
        Ht[scol +  8][srow] = c.x; Ht[scol +  9][srow] = c.y;
        Ht[scol + 10][srow] = c.z; Ht[scol + 11][srow] = c.w;
        Ht[scol + 12][srow] = d.x; Ht[scol + 13][srow] = d.y;
        Ht[scol + 14][srow] = d.z; Ht[scol + 15][srow] = d.w;
        __syncthreads();   // writes visible

        const float* zp = Zn + (size_t)ek * NC + c4;
#pragma unroll 4
        for (int k = 0; k < 64; ++k) {
            const float4 h = *reinterpret_cast<const float4*>(&Ht[k][v4]);
            const float4 z = *reinterpret_cast<const float4*>(zp);
            zp += NC;
            ds[0] += h.x; ds[1] += h.y; ds[2] += h.z; ds[3] += h.w;
            acc[0][0] += h.x * z.x; acc[0][1] += h.x * z.y; acc[0][2] += h.x * z.z; acc[0][3] += h.x * z.w;
            acc[1][0] += h.y * z.x; acc[1][1] += h.y * z.y; acc[1][2] += h.y * z.z; acc[1][3] += h.y * z.w;
            acc[2][0] += h.z * z.x; acc[2][1] += h.z * z.y; acc[2][2] += h.z * z.z; acc[2][3] += h.z * z.w;
            acc[3][0] += h.w * z.x; acc[3][1] += h.w * z.y; acc[3][2] += h.w * z.z; acc[3][3] += h.w * z.w;
        }
    }

    const int sp = blockIdx.y;
    float* pb = P3 + (((size_t)sp * N_B + n) * NV + v0 + v4) * NC + c4;
#pragma unroll
    for (int i = 0; i < 4; ++i)
        *reinterpret_cast<float4*>(pb + (size_t)i * NC) =
            make_float4(acc[i][0], acc[i][1], acc[i][2], acc[i][3]);

    if (c4 == 0) {
        float* db = dvP + ((size_t)sp * N_B + n) * NV + v0 + v4;
#pragma unroll
        for (int i = 0; i < 4; ++i) db[i] = ds[i];
    }
}

// ---------------------------------------------------------------------------
// Kernel 5: out = (sum_s P3) / dv + bias.  In-place safe when P3==out, nsp==1.
// ---------------------------------------------------------------------------
__global__ __launch_bounds__(256) void k_red3(const float* __restrict__ P3,
                                              const float* __restrict__ dvP,
                                              const float* __restrict__ bias,
                                              float* __restrict__ out, int nsp) {
    const int i = blockIdx.x * 256 + threadIdx.x;     // float4 index
    const int row = i >> 4;                           // n*V + v
    float4 a = make_float4(0.f, 0.f, 0.f, 0.f);
    float d = 0.f;
    for (int s = 0; s < nsp; ++s) {
        const float4 p = reinterpret_cast<const float4*>(P3)[(size_t)s * (N_B * NV * NC / 4) + i];
        a.x += p.x; a.y += p.y; a.z += p.z; a.w += p.w;
        d += dvP[(size_t)s * (N_B * NV) + row];
    }
    const float r = 1.0f / d;
    const float4 b = *reinterpret_cast<const float4*>(&bias[(i & 15) * 4]);
    a.x = a.x * r + b.x;
    a.y = a.y * r + b.y;
    a.z = a.z * r + b.z;
    a.w = a.w * r + b.w;
    reinterpret_cast<float4*>(out)[i] = a;
}

// ---------------------------------------------------------------------------
extern "C" void kernel_launch(void* const* d_in, const int* in_sizes, int n_in,
                              void* d_out, int out_size, void* d_ws, size_t ws_size,
                              hipStream_t stream) {
    const float* x     = (const float*)d_in[0];
    const float* H     = (const float*)d_in[1];
    const float* theta = (const float*)d_in[2];
    const float* bias  = (const float*)d_in[3];
    float* out = (float*)d_out;

    const size_t yN  = (size_t)N_B * NV * NC;   // 1,048,576
    const size_t zN  = (size_t)N_B * NE * NC;   //   524,288
    const size_t deN = (size_t)N_B * NE;        //     8,192
    const size_t dvN = (size_t)N_B * NV;        //    16,384

    auto need = [&](int a, int b) -> size_t {
        return (yN + (size_t)a * zN + (size_t)a * deN + zN + (size_t)b * yN + (size_t)b * dvN) * 4;
    };

    int s2, s3; bool minimal = false;
    if      (ws_size >= need(16, 8)) { s2 = 16; s3 = 8; }
    else if (ws_size >= need(8, 4))  { s2 = 8;  s3 = 4; }
    else if (ws_size >= need(4, 2))  { s2 = 4;  s3 = 2; }
    else if (ws_size >= need(2, 1))  { s2 = 2;  s3 = 1; }
    else                             { s2 = 1;  s3 = 1; minimal = true; }

    float* Y   = (float*)d_ws;
    float* P2  = Y + yN;
    float* deP = P2 + (size_t)s2 * zN;
    float *Zb, *P3, *dvP;
    if (minimal) {
        Zb  = P2;               // red2 in place (s2==1)
        dvP = deP + deN;
        P3  = out;              // red3 in place (s3==1)
    } else {
        Zb  = deP + (size_t)s2 * deN;
        P3  = Zb + zN;
        dvP = P3 + (size_t)s3 * yN;
    }

    k_xtheta<<<dim3(N_B * NV / 4), 256, 0, stream>>>(x, theta, Y);
    k_v2e<<<dim3(NE / 64, s2, N_B), 256, 0, stream>>>(H, Y, P2, deP);
    k_red2<<<dim3((int)(zN / 4 / 256)), 256, 0, stream>>>(P2, deP, Zb, s2);
    k_e2v<<<dim3(NV / 64, s3, N_B), 256, 0, stream>>>(H, Zb, P3, dvP);
    k_red3<<<dim3((int)(yN / 4 / 256)), 256, 0, stream>>>(P3, dvP, bias, out, s3);
}

// Round 5
// 173.179 us; speedup vs baseline: 6.4397x; 1.3960x over previous
//
#include <hip/hip_runtime.h>
#include <hip/hip_bf16.h>
#include <stdint.h>

#define N_B 4
#define NV 4096
#define NE 2048
#define NC 64

typedef float    f32x4  __attribute__((ext_vector_type(4)));
typedef __bf16   bf16x8 __attribute__((ext_vector_type(8)));
typedef unsigned short u16;
typedef u16      u16x8  __attribute__((ext_vector_type(8)));
typedef uint32_t u32x4  __attribute__((ext_vector_type(4)));

__device__ __forceinline__ u16 f2bf_rne(float f) {
    uint32_t u = __builtin_bit_cast(uint32_t, f);
    u += 0x7FFFu + ((u >> 16) & 1u);
    return (u16)(u >> 16);
}
__device__ __forceinline__ float bf2f(u16 h) {
    uint32_t u = ((uint32_t)h) << 16;
    return __builtin_bit_cast(float, u);
}
__device__ __forceinline__ f32x4 mfma_bf16(u16x8 a, u16x8 b, f32x4 c) {
    return __builtin_amdgcn_mfma_f32_16x16x32_bf16(
        __builtin_bit_cast(bf16x8, a), __builtin_bit_cast(bf16x8, b), c, 0, 0, 0);
}

// ---------------------------------------------------------------------------
// Kernel 1: Yht_{h,l}[n][c][v] (bf16 hi/lo) = transpose of x@theta.
// Block = 64v x 64c tile. Thread = 4c x 4v.
// ---------------------------------------------------------------------------
__global__ __launch_bounds__(256) void k_xtheta(const float* __restrict__ x,
                                                const float* __restrict__ th,
                                                u16* __restrict__ Yh,
                                                u16* __restrict__ Yl) {
    __shared__ float xs[64][65];   // [v][k]
    __shared__ float ts[64][65];   // [k][c]
    const int t = threadIdx.x;
    const int n  = blockIdx.x >> 6;
    const int v0 = (blockIdx.x & 63) * 64;

#pragma unroll
    for (int i = 0; i < 4; ++i) {
        const int idx = i * 256 + t;
        const int row = idx >> 4, q = (idx & 15) * 4;
        const float4 xv = *(const float4*)&x[((size_t)(n * NV + v0 + row)) * 64 + q];
        const float4 tv = *(const float4*)&th[(size_t)row * 64 + q];
        xs[row][q] = xv.x; xs[row][q + 1] = xv.y; xs[row][q + 2] = xv.z; xs[row][q + 3] = xv.w;
        ts[row][q] = tv.x; ts[row][q + 1] = tv.y; ts[row][q + 2] = tv.z; ts[row][q + 3] = tv.w;
    }
    __syncthreads();

    const int v4 = (t & 15) * 4;
    const int c4 = (t >> 4) * 4;
    float acc[4][4] = {};   // [c][v]
#pragma unroll
    for (int k = 0; k < 64; ++k) {
        float tv[4], xv[4];
#pragma unroll
        for (int i = 0; i < 4; ++i) { tv[i] = ts[k][c4 + i]; xv[i] = xs[v4 + i][k]; }
#pragma unroll
        for (int i = 0; i < 4; ++i)
#pragma unroll
            for (int j = 0; j < 4; ++j) acc[i][j] += tv[i] * xv[j];
    }
#pragma unroll
    for (int i = 0; i < 4; ++i) {
        ushort4 hi, lo;
        u16 h;
        h = f2bf_rne(acc[i][0]); hi.x = h; lo.x = f2bf_rne(acc[i][0] - bf2f(h));
        h = f2bf_rne(acc[i][1]); hi.y = h; lo.y = f2bf_rne(acc[i][1] - bf2f(h));
        h = f2bf_rne(acc[i][2]); hi.z = h; lo.z = f2bf_rne(acc[i][2] - bf2f(h));
        h = f2bf_rne(acc[i][3]); hi.w = h; lo.w = f2bf_rne(acc[i][3] - bf2f(h));
        const size_t o = ((size_t)n * 64 + c4 + i) * NV + v0 + v4;
        *(ushort4*)&Yh[o] = hi;
        *(ushort4*)&Yl[o] = lo;
    }
}

// ---------------------------------------------------------------------------
// Kernel 2: vertex->edge MFMA partials.
//   P2[sp][n][c][e] = sum_{v in Krange} H[n,v,e]*(Yh+Yl)[n,v,c]
//   deP[sp][n][e]   = sum H (via constant all-ones B fragment)
// Block 64e x 64c, 4 waves (wave = 16e x 64c), K-step 32 v.
// A = H^T via LDS transpose (80B padded rows, 2-way conflicts = free).
// B = Yht direct 16B global loads. Next-step operands reg-prefetched.
// ---------------------------------------------------------------------------
__global__ __launch_bounds__(256) void k_v2e(const float* __restrict__ H,
                                             const u16* __restrict__ Yh,
                                             const u16* __restrict__ Yl,
                                             float* __restrict__ P2,
                                             float* __restrict__ deP) {
    __shared__ u16 Hlds[64 * 40];   // [e][40 bf16 slots], 80B rows, 5 KB

    const int n   = blockIdx.z;
    const int e0  = blockIdx.x * 64;
    const int sp  = blockIdx.y;
    const int krange = NV / gridDim.y;
    const int kk0 = sp * krange;
    const int S   = krange / 32;

    const int t  = threadIdx.x;
    const int w  = t >> 6, l = t & 63;
    const int lq = l >> 4, lr = l & 15;

    const float* __restrict__ Hn = H + (size_t)n * NV * NE;

    // staging role: v-pair sr (rows 2sr,2sr+1), e-chunk sec (4 e)
    const int sr = t & 15;
    const int sec = t >> 4;

    const u16* __restrict__ ybh = Yh + ((size_t)n * 64 + lr) * NV + lq * 8;
    const u16* __restrict__ ybl = Yl + ((size_t)n * 64 + lr) * NV + lq * 8;

    f32x4 acc0 = {0.f,0.f,0.f,0.f}, acc1 = acc0, acc2 = acc0, acc3 = acc0, accd = acc0;
    const u16x8 bones = {0x3F80,0x3F80,0x3F80,0x3F80,0x3F80,0x3F80,0x3F80,0x3F80};

    // prologue loads (step 0)
    const float* hs0 = Hn + (size_t)(kk0 + 2 * sr) * NE + e0 + sec * 4;
    float4 ha = *(const float4*)hs0;
    float4 hb = *(const float4*)(hs0 + NE);
    u16x8 bh0 = *(const u16x8*)(ybh + kk0);
    u16x8 bh1 = *(const u16x8*)(ybh + 16 * NV + kk0);
    u16x8 bh2 = *(const u16x8*)(ybh + 32 * NV + kk0);
    u16x8 bh3 = *(const u16x8*)(ybh + 48 * NV + kk0);
    u16x8 bl0 = *(const u16x8*)(ybl + kk0);
    u16x8 bl1 = *(const u16x8*)(ybl + 16 * NV + kk0);
    u16x8 bl2 = *(const u16x8*)(ybl + 32 * NV + kk0);
    u16x8 bl3 = *(const u16x8*)(ybl + 48 * NV + kk0);

    const int a_off = (w * 16 + lr) * 40 + lq * 8;

    for (int s = 0; s < S; ++s) {
        __syncthreads();   // previous step's A-reads done
        {
            uint32_t* hw = (uint32_t*)Hlds;
            const uint32_t* pa = (const uint32_t*)&ha;
            const uint32_t* pb = (const uint32_t*)&hb;
#pragma unroll
            for (int i = 0; i < 4; ++i) {
                const uint32_t v = (pa[i] >> 16) | (pb[i] & 0xFFFF0000u);  // bf16(v=2sr)|bf16(2sr+1)<<16
                hw[(sec * 4 + i) * 20 + sr] = v;
            }
        }
        __syncthreads();

        // issue next-step loads (hidden under MFMA phase)
        float4 han, hbn;
        u16x8 bh0n, bh1n, bh2n, bh3n, bl0n, bl1n, bl2n, bl3n;
        const int vn = kk0 + (s + 1) * 32;
        if (s + 1 < S) {
            const float* hs = Hn + (size_t)(vn + 2 * sr) * NE + e0 + sec * 4;
            han = *(const float4*)hs;
            hbn = *(const float4*)(hs + NE);
            bh0n = *(const u16x8*)(ybh + vn);
            bh1n = *(const u16x8*)(ybh + 16 * NV + vn);
            bh2n = *(const u16x8*)(ybh + 32 * NV + vn);
            bh3n = *(const u16x8*)(ybh + 48 * NV + vn);
            bl0n = *(const u16x8*)(ybl + vn);
            bl1n = *(const u16x8*)(ybl + 16 * NV + vn);
            bl2n = *(const u16x8*)(ybl + 32 * NV + vn);
            bl3n = *(const u16x8*)(ybl + 48 * NV + vn);
        }

        const u16x8 afrag = *(const u16x8*)(Hlds + a_off);
        acc0 = mfma_bf16(afrag, bh0, acc0);
        acc0 = mfma_bf16(afrag, bl0, acc0);
        acc1 = mfma_bf16(afrag, bh1, acc1);
        acc1 = mfma_bf16(afrag, bl1, acc1);
        acc2 = mfma_bf16(afrag, bh2, acc2);
        acc2 = mfma_bf16(afrag, bl2, acc2);
        acc3 = mfma_bf16(afrag, bh3, acc3);
        acc3 = mfma_bf16(afrag, bl3, acc3);
        accd = mfma_bf16(afrag, bones, accd);

        if (s + 1 < S) {
            ha = han; hb = hbn;
            bh0 = bh0n; bh1 = bh1n; bh2 = bh2n; bh3 = bh3n;
            bl0 = bl0n; bl1 = bl1n; bl2 = bl2n; bl3 = bl3n;
        }
    }

    // D frag: row e = e0 + w*16 + lq*4 + r (r=reg), col c = f*16 + lr
    const int e_lane = e0 + w * 16 + lq * 4;
    float* pbase = P2 + (((size_t)sp * N_B + n) * 64) * NE;
    *(f32x4*)&pbase[(size_t)(0 * 16 + lr) * NE + e_lane] = acc0;
    *(f32x4*)&pbase[(size_t)(1 * 16 + lr) * NE + e_lane] = acc1;
    *(f32x4*)&pbase[(size_t)(2 * 16 + lr) * NE + e_lane] = acc2;
    *(f32x4*)&pbase[(size_t)(3 * 16 + lr) * NE + e_lane] = acc3;
    if (lr == 0)
        *(f32x4*)&deP[((size_t)sp * N_B + n) * NE + e_lane] = accd;
}

// ---------------------------------------------------------------------------
// Kernel 3: Z_{h,l}[n][c][e] = bf16 hi/lo of (sum_sp P2)/de
// ---------------------------------------------------------------------------
__global__ __launch_bounds__(256) void k_red2(const float* __restrict__ P2,
                                              const float* __restrict__ deP,
                                              u16* __restrict__ Zh,
                                              u16* __restrict__ Zl, int nsp) {
    const int i = blockIdx.x * 256 + threadIdx.x;   // 0..131071
    const int row = i >> 9;                          // n*64 + c
    const int e4  = (i & 511) * 4;
    const int n   = row >> 6;

    float4 a = make_float4(0.f, 0.f, 0.f, 0.f);
    float4 d = make_float4(0.f, 0.f, 0.f, 0.f);
    for (int sp = 0; sp < nsp; ++sp) {
        const float4 p = *(const float4*)&P2[((size_t)sp * 256 + row) * NE + e4];
        const float4 q = *(const float4*)&deP[((size_t)sp * N_B + n) * NE + e4];
        a.x += p.x; a.y += p.y; a.z += p.z; a.w += p.w;
        d.x += q.x; d.y += q.y; d.z += q.z; d.w += q.w;
    }
    float z[4] = {a.x / d.x, a.y / d.y, a.z / d.z, a.w / d.w};
    ushort4 hi, lo;
    u16 h;
    h = f2bf_rne(z[0]); hi.x = h; lo.x = f2bf_rne(z[0] - bf2f(h));
    h = f2bf_rne(z[1]); hi.y = h; lo.y = f2bf_rne(z[1] - bf2f(h));
    h = f2bf_rne(z[2]); hi.z = h; lo.z = f2bf_rne(z[2] - bf2f(h));
    h = f2bf_rne(z[3]); hi.w = h; lo.w = f2bf_rne(z[3] - bf2f(h));
    *(ushort4*)&Zh[(size_t)row * NE + e4] = hi;
    *(ushort4*)&Zl[(size_t)row * NE + e4] = lo;
}

// ---------------------------------------------------------------------------
// Kernel 4: edge->vertex MFMA partials. NO LDS, no barriers.
//   P3[sp][n][c][v] = sum_{e in Krange} H[n,v,e]*(Zh+Zl)[n,e,c]
//   dvP[sp][n][v]   = sum H (ones fragment)
// A = H direct (k=e contiguous): 2 float4 loads/lane -> bf16 pack.
// B = Zht direct 16B loads (L2 resident). Reg-prefetch next step.
// ---------------------------------------------------------------------------
__global__ __launch_bounds__(256) void k_e2v(const float* __restrict__ H,
                                             const u16* __restrict__ Zh,
                                             const u16* __restrict__ Zl,
                                             float* __restrict__ P3,
                                             float* __restrict__ dvP) {
    const int n   = blockIdx.z;
    const int v0  = blockIdx.x * 64;
    const int sp  = blockIdx.y;
    const int krange = NE / gridDim.y;
    const int kk0 = sp * krange;
    const int S   = krange / 32;

    const int t  = threadIdx.x;
    const int w  = t >> 6, l = t & 63;
    const int lq = l >> 4, lr = l & 15;

    const int vrow = v0 + w * 16 + lr;
    const float* __restrict__ ap = H + ((size_t)n * NV + vrow) * NE + lq * 8;
    const u16* __restrict__ zbh = Zh + ((size_t)n * 64 + lr) * NE + lq * 8;
    const u16* __restrict__ zbl = Zl + ((size_t)n * 64 + lr) * NE + lq * 8;

    f32x4 acc0 = {0.f,0.f,0.f,0.f}, acc1 = acc0, acc2 = acc0, acc3 = acc0, accd = acc0;
    const u16x8 bones = {0x3F80,0x3F80,0x3F80,0x3F80,0x3F80,0x3F80,0x3F80,0x3F80};

    float4 a0 = *(const float4*)(ap + kk0);
    float4 a1 = *(const float4*)(ap + kk0 + 4);
    u16x8 bh0 = *(const u16x8*)(zbh + kk0);
    u16x8 bh1 = *(const u16x8*)(zbh + 16 * NE + kk0);
    u16x8 bh2 = *(const u16x8*)(zbh + 32 * NE + kk0);
    u16x8 bh3 = *(const u16x8*)(zbh + 48 * NE + kk0);
    u16x8 bl0 = *(const u16x8*)(zbl + kk0);
    u16x8 bl1 = *(const u16x8*)(zbl + 16 * NE + kk0);
    u16x8 bl2 = *(const u16x8*)(zbl + 32 * NE + kk0);
    u16x8 bl3 = *(const u16x8*)(zbl + 48 * NE + kk0);

    for (int s = 0; s < S; ++s) {
        float4 a0n, a1n;
        u16x8 bh0n, bh1n, bh2n, bh3n, bl0n, bl1n, bl2n, bl3n;
        const int en = kk0 + (s + 1) * 32;
        if (s + 1 < S) {
            a0n = *(const float4*)(ap + en);
            a1n = *(const float4*)(ap + en + 4);
            bh0n = *(const u16x8*)(zbh + en);
            bh1n = *(const u16x8*)(zbh + 16 * NE + en);
            bh2n = *(const u16x8*)(zbh + 32 * NE + en);
            bh3n = *(const u16x8*)(zbh + 48 * NE + en);
            bl0n = *(const u16x8*)(zbl + en);
            bl1n = *(const u16x8*)(zbl + 16 * NE + en);
            bl2n = *(const u16x8*)(zbl + 32 * NE + en);
            bl3n = *(const u16x8*)(zbl + 48 * NE + en);
        }

        const uint32_t* u0 = (const uint32_t*)&a0;
        const uint32_t* u1 = (const uint32_t*)&a1;
        const u32x4 aw = { (u0[0] >> 16) | (u0[1] & 0xFFFF0000u),
                           (u0[2] >> 16) | (u0[3] & 0xFFFF0000u),
                           (u1[0] >> 16) | (u1[1] & 0xFFFF0000u),
                           (u1[2] >> 16) | (u1[3] & 0xFFFF0000u) };
        const u16x8 afrag = __builtin_bit_cast(u16x8, aw);

        acc0 = mfma_bf16(afrag, bh0, acc0);
        acc0 = mfma_bf16(afrag, bl0, acc0);
        acc1 = mfma_bf16(afrag, bh1, acc1);
        acc1 = mfma_bf16(afrag, bl1, acc1);
        acc2 = mfma_bf16(afrag, bh2, acc2);
        acc2 = mfma_bf16(afrag, bl2, acc2);
        acc3 = mfma_bf16(afrag, bh3, acc3);
        acc3 = mfma_bf16(afrag, bl3, acc3);
        accd = mfma_bf16(afrag, bones, accd);

        if (s + 1 < S) {
            a0 = a0n; a1 = a1n;
            bh0 = bh0n; bh1 = bh1n; bh2 = bh2n; bh3 = bh3n;
            bl0 = bl0n; bl1 = bl1n; bl2 = bl2n; bl3 = bl3n;
        }
    }

    // D frag: row v = v0 + w*16 + lq*4 + r, col c = f*16 + lr
    const int v_lane = v0 + w * 16 + lq * 4;
    float* pbase = P3 + (((size_t)sp * N_B + n) * 64) * NV;
    *(f32x4*)&pbase[(size_t)(0 * 16 + lr) * NV + v_lane] = acc0;
    *(f32x4*)&pbase[(size_t)(1 * 16 + lr) * NV + v_lane] = acc1;
    *(f32x4*)&pbase[(size_t)(2 * 16 + lr) * NV + v_lane] = acc2;
    *(f32x4*)&pbase[(size_t)(3 * 16 + lr) * NV + v_lane] = acc3;
    if (lr == 0)
        *(f32x4*)&dvP[((size_t)sp * N_B + n) * NV + v_lane] = accd;
}

// ---------------------------------------------------------------------------
// Kernel 5: out[n][v][c] = (sum_sp P3[sp][n][c][v]) / dv + bias  (transpose)
// Block = (v-tile 64) x (full 64 c), 512 threads, LDS transpose.
// ---------------------------------------------------------------------------
__global__ __launch_bounds__(512) void k_red3(const float* __restrict__ P3,
                                              const float* __restrict__ dvP,
                                              const float* __restrict__ bias,
                                              float* __restrict__ out, int nsp) {
    __shared__ float lt[64][68];
    const int n  = blockIdx.y;
    const int v0 = blockIdx.x * 64;
    const int t  = threadIdx.x;

    {
        const int c   = t >> 3;
        const int vch = (t & 7) * 8;
        float4 s0 = make_float4(0.f, 0.f, 0.f, 0.f), s1 = s0;
        for (int sp = 0; sp < nsp; ++sp) {
            const size_t base = (((size_t)sp * N_B + n) * 64 + c) * NV + v0 + vch;
            const float4 p0 = *(const float4*)&P3[base];
            const float4 p1 = *(const float4*)&P3[base + 4];
            s0.x += p0.x; s0.y += p0.y; s0.z += p0.z; s0.w += p0.w;
            s1.x += p1.x; s1.y += p1.y; s1.z += p1.z; s1.w += p1.w;
        }
        *(float4*)&lt[c][vch]     = s0;
        *(float4*)&lt[c][vch + 4] = s1;
    }
    // dv for the write-phase row
    const int vw  = t >> 3;
    const int cch = (t & 7) * 8;
    float dsum = 0.f;
    for (int sp = 0; sp < nsp; ++sp)
        dsum += dvP[((size_t)sp * N_B + n) * NV + v0 + vw];
    __syncthreads();

    const float rdv = 1.0f / dsum;
    const float4 b0 = *(const float4*)&bias[cch];
    const float4 b1 = *(const float4*)&bias[cch + 4];
    float4 o0, o1;
    o0.x = lt[cch + 0][vw] * rdv + b0.x;
    o0.y = lt[cch + 1][vw] * rdv + b0.y;
    o0.z = lt[cch + 2][vw] * rdv + b0.z;
    o0.w = lt[cch + 3][vw] * rdv + b0.w;
    o1.x = lt[cch + 4][vw] * rdv + b1.x;
    o1.y = lt[cch + 5][vw] * rdv + b1.y;
    o1.z = lt[cch + 6][vw] * rdv + b1.z;
    o1.w = lt[cch + 7][vw] * rdv + b1.w;
    float* dst = out + ((size_t)n * NV + v0 + vw) * 64 + cch;
    *(float4*)dst       = o0;
    *(float4*)(dst + 4) = o1;
}

// ---------------------------------------------------------------------------
extern "C" void kernel_launch(void* const* d_in, const int* in_sizes, int n_in,
                              void* d_out, int out_size, void* d_ws, size_t ws_size,
                              hipStream_t stream) {
    const float* x     = (const float*)d_in[0];
    const float* H     = (const float*)d_in[1];
    const float* theta = (const float*)d_in[2];
    const float* bias  = (const float*)d_in[3];
    float* out = (float*)d_out;

    const size_t yE  = (size_t)N_B * 64 * NV;   // 1,048,576 elems
    const size_t zE  = (size_t)N_B * 64 * NE;   //   524,288
    const size_t deE = (size_t)N_B * NE;
    const size_t dvE = (size_t)N_B * NV;

    u16* Yh = (u16*)d_ws;
    u16* Yl = Yh + yE;
    u16* Zh = Yl + yE;
    u16* Zl = Zh + zE;
    float* fbase = (float*)(Zl + zE);
    const size_t fixed_bytes = (2 * yE + 2 * zE) * sizeof(u16);
    const size_t avail_f = (ws_size > fixed_bytes) ? (ws_size - fixed_bytes) / 4 : 0;

    const size_t unit2 = zE + deE;   // per s2 (floats)
    const size_t unit3 = yE + dvE;   // per s3 (floats)
    int s2 = 1, s3 = 1;
    if      (avail_f >= 8 * unit2 + 4 * unit3) { s2 = 8; s3 = 4; }
    else if (avail_f >= 4 * unit2 + 4 * unit3) { s2 = 4; s3 = 4; }
    else if (avail_f >= 4 * unit2 + 2 * unit3) { s2 = 4; s3 = 2; }
    else if (avail_f >= 2 * unit2 + 2 * unit3) { s2 = 2; s3 = 2; }
    else if (avail_f >= 2 * unit2 + 1 * unit3) { s2 = 2; s3 = 1; }

    float* P2  = fbase;
    float* deP = P2 + (size_t)s2 * zE;
    float* P3  = deP + (size_t)s2 * deE;
    float* dvP = P3 + (size_t)s3 * yE;

    k_xtheta<<<dim3(N_B * NV / 64), 256, 0, stream>>>(x, theta, Yh, Yl);
    k_v2e<<<dim3(NE / 64, s2, N_B), 256, 0, stream>>>(H, Yh, Yl, P2, deP);
    k_red2<<<dim3((int)(zE / 4 / 256)), 256, 0, stream>>>(P2, deP, Zh, Zl, s2);
    k_e2v<<<dim3(NV / 64, s3, N_B), 256, 0, stream>>>(H, Zh, Zl, P3, dvP);
    k_red3<<<dim3(NV / 64, N_B), 512, 0, stream>>>(P3, dvP, bias, out, s3);
}